// Round 2
// baseline (1778.889 us; speedup 1.0000x reference)
//
#include <hip/hip_runtime.h>

#define NTOK   32768
#define DDIM   512
#define KCODES 8192
#define DK     (DDIM * KCODES)      // 4194304
#define DECAYF 0.8f
#define EPSF   1e-5f

using short8 = __attribute__((ext_vector_type(8))) short;
using f32x4  = __attribute__((ext_vector_type(4))) float;

// ---------------- ws layout (float offsets) ----------------
#define WS_ESUMT   0                          // [K][D] fp32 (fully written by segsum)
#define WS_ONEHOT  DK                         // [K] (zeroed)
#define WS_ENORM   (DK + 8192)                // [K] (zeroed, atomic accum)
#define WS_SCAL    (DK + 16384)               // [16]: 0=loss, 1=nsum (zeroed)
#define WS_PART    (DK + 16400)               // NTOK u64, memset 0xFF (= u64 max)
#define WS_EMBEDT  (WS_PART + 2 * NTOK)       // [K][D] fp32 transposed codebook
#define WS_EHI     (WS_EMBEDT + DK)           // [K][D] bf16 hi (DK ushorts)
#define WS_ELO     (WS_EHI + DK / 2)          // [K][D] bf16 lo

__device__ __forceinline__ unsigned short bf16rne(float f) {
  unsigned u = __float_as_uint(f);
  unsigned r = u + 0x7FFFu + ((u >> 16) & 1u);
  return (unsigned short)(r >> 16);
}

__device__ __forceinline__ void gload_lds16(const unsigned short* g, unsigned short* l) {
  __builtin_amdgcn_global_load_lds(
      (const __attribute__((address_space(1))) unsigned int*)g,
      (__attribute__((address_space(3))) unsigned int*)l, 16, 0, 0);
}

// ============ K1: split x into bf16 hi/lo ============
__global__ __launch_bounds__(256) void split_x_kernel(
    const float* __restrict__ x, unsigned short* __restrict__ hi,
    unsigned short* __restrict__ lo) {
  const size_t i = ((size_t)blockIdx.x * 256 + threadIdx.x) * 8;
  const float4 v0 = *(const float4*)&x[i];
  const float4 v1 = *(const float4*)&x[i + 4];
  const float v[8] = {v0.x, v0.y, v0.z, v0.w, v1.x, v1.y, v1.z, v1.w};
  unsigned short h[8], l[8];
#pragma unroll
  for (int j = 0; j < 8; ++j) {
    h[j] = bf16rne(v[j]);
    l[j] = bf16rne(v[j] - __uint_as_float((unsigned)h[j] << 16));
  }
  uint4 H, L;
  H.x = h[0] | ((unsigned)h[1] << 16); H.y = h[2] | ((unsigned)h[3] << 16);
  H.z = h[4] | ((unsigned)h[5] << 16); H.w = h[6] | ((unsigned)h[7] << 16);
  L.x = l[0] | ((unsigned)l[1] << 16); L.y = l[2] | ((unsigned)l[3] << 16);
  L.z = l[4] | ((unsigned)l[5] << 16); L.w = l[6] | ((unsigned)l[7] << 16);
  *(uint4*)&hi[i] = H;
  *(uint4*)&lo[i] = L;
}

// ============ K2: transpose embed [D][K]->[K][D] fp32 + bf16 hi/lo + e_norm ============
__global__ __launch_bounds__(256) void transpose_split_kernel(
    const float* __restrict__ embed, float* __restrict__ embedT,
    unsigned short* __restrict__ ehi, unsigned short* __restrict__ elo,
    float* __restrict__ e_norm) {
  __shared__ float tile[32][33];
  __shared__ float part[8][32];
  const int k0 = blockIdx.x * 32;
  const int d0 = blockIdx.y * 32;
  const int tx = threadIdx.x;   // 0..31
  const int ty = threadIdx.y;   // 0..7
  float sq = 0.f;
#pragma unroll
  for (int j = 0; j < 4; ++j) {
    const int dl = ty + j * 8;
    const float v = embed[(size_t)(d0 + dl) * KCODES + k0 + tx];
    tile[dl][tx] = v;
    sq += v * v;
  }
  part[ty][tx] = sq;
  __syncthreads();
  if (ty == 0) {
    float s = 0.f;
#pragma unroll
    for (int j = 0; j < 8; ++j) s += part[j][tx];
    atomicAdd(&e_norm[k0 + tx], s);
  }
#pragma unroll
  for (int j = 0; j < 4; ++j) {
    const int kl = ty + j * 8;
    const size_t idx = (size_t)(k0 + kl) * DDIM + d0 + tx;
    const float v = tile[tx][kl];
    embedT[idx] = v;
    const unsigned short h = bf16rne(v);
    ehi[idx] = h;
    elo[idx] = bf16rne(v - __uint_as_float((unsigned)h << 16));
  }
}

// ============ K3: fused 3-product bf16-split MFMA dist GEMM + argmin ============
// (reverted to the proven 939 us structure: 128x128 tile, BK=32, 4 waves,
//  2 barriers/K-step, 32 KB LDS -> multi-block/CU overlap)
__global__ __launch_bounds__(256) void argmin_mfma_kernel(
    const unsigned short* __restrict__ xhi, const unsigned short* __restrict__ xlo,
    const unsigned short* __restrict__ ehi, const unsigned short* __restrict__ elo,
    const float* __restrict__ e_norm, unsigned long long* __restrict__ partials) {
  __shared__ unsigned short Ahs[128 * 32];   // 8 KB each
  __shared__ unsigned short Als[128 * 32];
  __shared__ unsigned short Bhs[128 * 32];
  __shared__ unsigned short Bls[128 * 32];

  const int t    = threadIdx.x;
  const int wid  = t >> 6;
  const int lid  = t & 63;
  const int kblk = blockIdx.x;              // 0..63
  const int tokbase = blockIdx.y * 128;
  const int kbase   = kblk * 128;

  const int wrow = wid >> 1, wcol = wid & 1;    // 2x2 wave grid, 64x64 each
  const int m16  = lid & 15, kq = lid >> 4;

  // staging lane mapping: row-within-chunk + swizzled global colgroup
  const int srow = lid >> 2;                                  // 0..15
  const int gcol = ((lid & 3) ^ ((srow >> 1) & 3)) * 8;       // swizzled source

  // ds_read swizzle for fragment loads
  const int fsw = (kq ^ ((m16 >> 1) & 3)) * 8;

  f32x4 acc[4][4];
#pragma unroll
  for (int i = 0; i < 4; ++i)
#pragma unroll
    for (int j = 0; j < 4; ++j) acc[i][j] = (f32x4)0.f;

  const unsigned short* Ahg = xhi + (size_t)tokbase * DDIM;
  const unsigned short* Alg = xlo + (size_t)tokbase * DDIM;
  const unsigned short* Bhg = ehi + (size_t)kbase * DDIM;
  const unsigned short* Blg = elo + (size_t)kbase * DDIM;

#pragma unroll 1
  for (int d0 = 0; d0 < DDIM; d0 += 32) {
    __syncthreads();
#pragma unroll
    for (int p = 0; p < 2; ++p) {
      const int chunk = wid + p * 4;                       // wave-uniform
      const size_t go = (size_t)(chunk * 16 + srow) * DDIM + d0 + gcol;
      gload_lds16(Ahg + go, &Ahs[chunk * 512]);
      gload_lds16(Alg + go, &Als[chunk * 512]);
      gload_lds16(Bhg + go, &Bhs[chunk * 512]);
      gload_lds16(Blg + go, &Bls[chunk * 512]);
    }
    __syncthreads();
    short8 bh[4], bl[4];
#pragma unroll
    for (int j = 0; j < 4; ++j) {
      const int r = (wcol * 64 + j * 16 + m16) * 32 + fsw;
      bh[j] = *(const short8*)&Bhs[r];
      bl[j] = *(const short8*)&Bls[r];
    }
#pragma unroll
    for (int i = 0; i < 4; ++i) {
      const int r = (wrow * 64 + i * 16 + m16) * 32 + fsw;
      const short8 ah = *(const short8*)&Ahs[r];
      const short8 al = *(const short8*)&Als[r];
#pragma unroll
      for (int j = 0; j < 4; ++j) {
        acc[i][j] = __builtin_amdgcn_mfma_f32_16x16x32_bf16(ah, bh[j], acc[i][j], 0, 0, 0);
        acc[i][j] = __builtin_amdgcn_mfma_f32_16x16x32_bf16(ah, bl[j], acc[i][j], 0, 0, 0);
        acc[i][j] = __builtin_amdgcn_mfma_f32_16x16x32_bf16(al, bh[j], acc[i][j], 0, 0, 0);
      }
    }
  }

  // ---- fused argmin epilogue: score = e_norm[k] - 2*dot ----
  float en[4];
#pragma unroll
  for (int j = 0; j < 4; ++j)
    en[j] = e_norm[kbase + wcol * 64 + j * 16 + m16];

  __syncthreads();
  unsigned long long* red = (unsigned long long*)Ahs;   // [128][2], 2 KB
#pragma unroll
  for (int i = 0; i < 4; ++i) {
#pragma unroll
    for (int r = 0; r < 4; ++r) {
      unsigned long long best = 0xFFFFFFFFFFFFFFFFull;
#pragma unroll
      for (int j = 0; j < 4; ++j) {
        const float s = en[j] - 2.0f * acc[i][j][r];
        unsigned u = __float_as_uint(s);
        u = (u & 0x80000000u) ? ~u : (u | 0x80000000u);  // orderable bits
        const unsigned k = (unsigned)(kbase + wcol * 64 + j * 16 + m16);
        const unsigned long long c = ((unsigned long long)u << 32) | k;
        best = (c < best) ? c : best;
      }
#pragma unroll
      for (int s = 1; s < 16; s <<= 1) {
        const unsigned long long c = __shfl_xor(best, s);
        best = (c < best) ? c : best;
      }
      if (m16 == 0)
        red[(wrow * 64 + i * 16 + kq * 4 + r) * 2 + wcol] = best;
    }
  }
  __syncthreads();
  if (t < 128) {
    const unsigned long long a0 = red[t * 2], a1 = red[t * 2 + 1];
    const unsigned long long m = (a0 < a1) ? a0 : a1;
    atomicMin(&partials[tokbase + t], m);
  }
}

// ============ K4a: gather quantize + loss + per-code counts ============
__global__ __launch_bounds__(128) void gather_quant_kernel(
    const float* __restrict__ x, const float* __restrict__ embedT,
    const unsigned long long* __restrict__ partials,
    float* __restrict__ quant_out, float* __restrict__ indf_out,
    float* __restrict__ onehot, float* __restrict__ scal) {
  const int n = blockIdx.x;
  __shared__ int s_ind;
  __shared__ float wsum[2];
  if (threadIdx.x == 0) {
    const int k = (int)(partials[n] & 0xFFFFFFFFull);
    s_ind = k;
    indf_out[n] = (float)k;
    atomicAdd(&onehot[k], 1.0f);
  }
  __syncthreads();
  const int k = s_ind;
  const int d4 = threadIdx.x * 4;    // 128 threads * 4 = 512 = DDIM
  const float4 e  = *(const float4*)&embedT[(size_t)k * DDIM + d4];
  const float4 xv = *(const float4*)&x[(size_t)n * DDIM + d4];
  *(float4*)&quant_out[(size_t)n * DDIM + d4] = e;
  const float dx0 = e.x - xv.x, dx1 = e.y - xv.y, dx2 = e.z - xv.z, dx3 = e.w - xv.w;
  float ls = dx0 * dx0 + dx1 * dx1 + dx2 * dx2 + dx3 * dx3;
#pragma unroll
  for (int off = 32; off > 0; off >>= 1) ls += __shfl_down(ls, off);
  if ((threadIdx.x & 63) == 0) wsum[threadIdx.x >> 6] = ls;
  __syncthreads();
  if (threadIdx.x == 0) atomicAdd(&scal[0], wsum[0] + wsum[1]);
}

// ============ K4b: exclusive prefix sum of counts -> offsets, cursor ============
__global__ __launch_bounds__(256) void scan_kernel(
    const float* __restrict__ counts, unsigned* __restrict__ offsets,
    unsigned* __restrict__ cursor) {
  __shared__ unsigned part[256];
  __shared__ unsigned base[256];
  const int t = threadIdx.x;
  unsigned c[32];
  unsigned s = 0;
#pragma unroll
  for (int j = 0; j < 32; ++j) {
    c[j] = (unsigned)counts[t * 32 + j];
    s += c[j];
  }
  part[t] = s;
  __syncthreads();
  if (t == 0) {
    unsigned r = 0;
    for (int i = 0; i < 256; ++i) { base[i] = r; r += part[i]; }
  }
  __syncthreads();
  unsigned r = base[t];
#pragma unroll
  for (int j = 0; j < 32; ++j) {
    offsets[t * 32 + j] = r;
    cursor[t * 32 + j]  = r;
    r += c[j];
  }
}

// ============ K4c: scatter token indices into per-code segments ============
__global__ __launch_bounds__(256) void scatter_kernel(
    const unsigned long long* __restrict__ partials,
    unsigned* __restrict__ cursor, unsigned* __restrict__ toklist) {
  const int n = blockIdx.x * 256 + threadIdx.x;
  const int k = (int)(partials[n] & 0xFFFFFFFFull);
  const unsigned pos = atomicAdd(&cursor[k], 1u);
  toklist[pos] = n;
}

// ============ K4d: per-code segment sum of x rows -> esumT [K][D] ============
__global__ __launch_bounds__(128) void segsum_kernel(
    const float* __restrict__ x, const float* __restrict__ counts,
    const unsigned* __restrict__ offsets, const unsigned* __restrict__ toklist,
    float* __restrict__ esumT) {
  const int c = blockIdx.x;
  const unsigned cnt = (unsigned)counts[c];
  const unsigned beg = offsets[c];
  const int d4 = threadIdx.x * 4;
  float4 acc = {0.f, 0.f, 0.f, 0.f};
  for (unsigned t = 0; t < cnt; ++t) {
    const unsigned n = toklist[beg + t];
    const float4 v = *(const float4*)&x[(size_t)n * DDIM + d4];
    acc.x += v.x; acc.y += v.y; acc.z += v.z; acc.w += v.w;
  }
  *(float4*)&esumT[(size_t)c * DDIM + d4] = acc;
}

// ============ K5: cluster-size EMA + total-count reduction ============
__global__ __launch_bounds__(256) void cluster_kernel(
    const float* __restrict__ cluster_size, const float* __restrict__ onehot,
    float* __restrict__ ncs_out, float* __restrict__ scal) {
  const int k = blockIdx.x * 256 + threadIdx.x;
  const float v = cluster_size[k] * DECAYF + (1.0f - DECAYF) * onehot[k];
  ncs_out[k] = v;
  float s = v;
#pragma unroll
  for (int off = 32; off > 0; off >>= 1) s += __shfl_down(s, off);
  __shared__ float w[4];
  if ((threadIdx.x & 63) == 0) w[threadIdx.x >> 6] = s;
  __syncthreads();
  if (threadIdx.x == 0) atomicAdd(&scal[1], w[0] + w[1] + w[2] + w[3]);
}

// ============ K6: new_embed_avg + new_embed via 32x33 LDS tile transpose ============
__global__ __launch_bounds__(256) void finalize_kernel(
    const float* __restrict__ embed_avg, const float* __restrict__ embed_sumT,
    const float* __restrict__ ncs, const float* __restrict__ scal,
    float* __restrict__ out_embed, float* __restrict__ out_avg,
    float* __restrict__ out_loss) {
  __shared__ float tile[32][33];
  const int k0 = blockIdx.x * 32;
  const int d0 = blockIdx.y * 32;
  const int tx = threadIdx.x;   // 0..31
  const int ty = threadIdx.y;   // 0..7
  // load esumT[k][d] tile, coalesced in d
#pragma unroll
  for (int j = 0; j < 4; ++j) {
    const int kl = ty + j * 8;
    tile[kl][tx] = embed_sumT[(size_t)(k0 + kl) * DDIM + d0 + tx];
  }
  const float nsum = scal[1];
  const float csv = (ncs[k0 + tx] + EPSF) / (nsum + (float)KCODES * EPSF) * nsum;
  __syncthreads();
#pragma unroll
  for (int j = 0; j < 4; ++j) {
    const int dl = ty + j * 8;
    const size_t idx = (size_t)(d0 + dl) * KCODES + k0 + tx;
    const float nea = DECAYF * embed_avg[idx] + (1.0f - DECAYF) * tile[tx][dl];
    out_avg[idx] = nea;
    out_embed[idx] = nea / csv;
  }
  if (blockIdx.x == 0 && blockIdx.y == 0 && tx == 0 && ty == 0)
    out_loss[0] = scal[0] * (1.0f / ((float)NTOK * (float)DDIM));
}

extern "C" void kernel_launch(void* const* d_in, const int* in_sizes, int n_in,
                              void* d_out, int out_size, void* d_ws, size_t ws_size,
                              hipStream_t stream) {
  (void)in_sizes; (void)n_in; (void)out_size; (void)ws_size;
  const float* x            = (const float*)d_in[0];   // [NTOK, 512]
  const float* embed        = (const float*)d_in[1];   // [D, K]
  const float* cluster_size = (const float*)d_in[2];   // [K]
  const float* embed_avg    = (const float*)d_in[3];   // [D, K]

  float* out = (float*)d_out;
  float* out_quant = out;                               // 16777216
  float* out_indf  = out + 16777216;                    // 32768
  float* out_loss  = out + 16777216 + 32768;            // 1
  float* out_embed = out + 16777216 + 32768 + 1;        // 4194304 (odd offset)
  float* out_ncs   = out_embed + DK;                    // 8192
  float* out_avg   = out_ncs + KCODES;                  // 4194304

  float* ws = (float*)d_ws;
  float* esumT  = ws + WS_ESUMT;
  float* onehot = ws + WS_ONEHOT;
  float* e_norm = ws + WS_ENORM;
  float* scal   = ws + WS_SCAL;
  unsigned long long* partials = (unsigned long long*)(ws + WS_PART);
  float* embedT = ws + WS_EMBEDT;
  unsigned short* ehi = (unsigned short*)(ws + WS_EHI);
  unsigned short* elo = (unsigned short*)(ws + WS_ELO);

  // sort scratch aliases the ehi region (dead after argmin_mfma_kernel)
  unsigned* offsets = (unsigned*)(ws + WS_EHI);         // [K]
  unsigned* cursor  = offsets + KCODES;                 // [K]
  unsigned* toklist = cursor + KCODES;                  // [NTOK]

  // x hi/lo scratch lives in the out_quant region; overwritten by gather later.
  unsigned short* xhi = (unsigned short*)d_out;
  unsigned short* xlo = xhi + (size_t)NTOK * DDIM;

  // zero only onehot/e_norm/scal (esumT is fully written by segsum_kernel)
  hipMemsetAsync((char*)d_ws + (size_t)DK * 4, 0, (size_t)16400 * 4, stream);
  hipMemsetAsync((char*)d_ws + (size_t)WS_PART * 4, 0xFF, (size_t)NTOK * 8, stream);

  split_x_kernel<<<NTOK * DDIM / 8 / 256, 256, 0, stream>>>(x, xhi, xlo);
  transpose_split_kernel<<<dim3(KCODES / 32, DDIM / 32), dim3(32, 8), 0, stream>>>(
      embed, embedT, ehi, elo, e_norm);

  argmin_mfma_kernel<<<dim3(64, 256), 256, 0, stream>>>(
      xhi, xlo, ehi, elo, e_norm, partials);

  gather_quant_kernel<<<NTOK, 128, 0, stream>>>(
      x, embedT, partials, out_quant, out_indf, onehot, scal);

  scan_kernel<<<1, 256, 0, stream>>>(onehot, offsets, cursor);
  scatter_kernel<<<NTOK / 256, 256, 0, stream>>>(partials, cursor, toklist);
  segsum_kernel<<<KCODES, 128, 0, stream>>>(x, onehot, offsets, toklist, esumT);

  cluster_kernel<<<KCODES / 256, 256, 0, stream>>>(cluster_size, onehot, out_ncs, scal);

  finalize_kernel<<<dim3(KCODES / 32, DDIM / 32), dim3(32, 8), 0, stream>>>(
      embed_avg, esumT, out_ncs, scal, out_embed, out_avg, out_loss);
}

// Round 3
// 1430.895 us; speedup vs baseline: 1.2432x; 1.2432x over previous
//
#include <hip/hip_runtime.h>

#define NTOK   32768
#define DDIM   512
#define KCODES 8192
#define DK     (DDIM * KCODES)      // 4194304
#define DECAYF 0.8f
#define EPSF   1e-5f

using short8 = __attribute__((ext_vector_type(8))) short;
using f32x4  = __attribute__((ext_vector_type(4))) float;

// ---------------- ws layout (float offsets) ----------------
// esumT [K][D] (zeroed in prep, atomic-accum in gather)
// onehot [K]   (zeroed in prep, atomic in gather)
// enp [16][K]  (plain-stored partial codebook norms, read by argmin)
// scal [64]    (0=loss accum; 2+b = cluster_size partial sums, b<32)
// partials NTOK u64 (0xFF-init in prep, atomicMin in argmin)
// ehi/elo [K][D] bf16 hi/lo codebook
#define WS_ESUMT  0
#define WS_ONEHOT DK
#define WS_ENP    (DK + 8192)
#define WS_SCAL   (DK + 8192 + 131072)
#define WS_PART   (WS_SCAL + 64)
#define WS_EHI    (WS_PART + 2 * NTOK)
#define WS_ELO    (WS_EHI + DK / 2)

__device__ __forceinline__ unsigned short bf16rne(float f) {
  unsigned u = __float_as_uint(f);
  unsigned r = u + 0x7FFFu + ((u >> 16) & 1u);
  return (unsigned short)(r >> 16);
}

__device__ __forceinline__ void gload_lds16(const unsigned short* g, unsigned short* l) {
  __builtin_amdgcn_global_load_lds(
      (const __attribute__((address_space(1))) unsigned int*)g,
      (__attribute__((address_space(3))) unsigned int*)l, 16, 0, 0);
}

// ============ K1: fused prep ============
// blocks [0,8192)          : split x into bf16 hi/lo
// blocks [8192,12288)      : transpose embed -> ehi/elo + enp partial norms
// blocks [12288,14336)     : zero esumT
// blocks [14336,14368)     : zero onehot, partials=0xFF, cs partial sums, scal[0]=0
__global__ __launch_bounds__(256) void prep_kernel(
    const float* __restrict__ x, const float* __restrict__ embed,
    const float* __restrict__ cluster_size,
    unsigned short* __restrict__ xhi, unsigned short* __restrict__ xlo,
    unsigned short* __restrict__ ehi, unsigned short* __restrict__ elo,
    float* __restrict__ enp, float* __restrict__ esumT,
    float* __restrict__ onehot, float* __restrict__ scal,
    unsigned long long* __restrict__ partials) {
  __shared__ float tile[32][33];
  __shared__ float part[8][32];
  __shared__ float w[4];
  const int bid = blockIdx.x;
  const int tid = threadIdx.x;

  if (bid < 8192) {
    // ---- split x ----
    const size_t i = ((size_t)bid * 256 + tid) * 8;
    const float4 v0 = *(const float4*)&x[i];
    const float4 v1 = *(const float4*)&x[i + 4];
    const float v[8] = {v0.x, v0.y, v0.z, v0.w, v1.x, v1.y, v1.z, v1.w};
    unsigned short h[8], l[8];
#pragma unroll
    for (int j = 0; j < 8; ++j) {
      h[j] = bf16rne(v[j]);
      l[j] = bf16rne(v[j] - __uint_as_float((unsigned)h[j] << 16));
    }
    uint4 H, L;
    H.x = h[0] | ((unsigned)h[1] << 16); H.y = h[2] | ((unsigned)h[3] << 16);
    H.z = h[4] | ((unsigned)h[5] << 16); H.w = h[6] | ((unsigned)h[7] << 16);
    L.x = l[0] | ((unsigned)l[1] << 16); L.y = l[2] | ((unsigned)l[3] << 16);
    L.z = l[4] | ((unsigned)l[5] << 16); L.w = l[6] | ((unsigned)l[7] << 16);
    *(uint4*)&xhi[i] = H;
    *(uint4*)&xlo[i] = L;
  } else if (bid < 8192 + 4096) {
    // ---- transpose embed tile + bf16 split + norm partials ----
    const int tb = bid - 8192;
    const int k0 = (tb & 255) * 32;
    const int d0 = (tb >> 8) * 32;
    const int tx = tid & 31;
    const int ty = tid >> 5;
    float sq = 0.f;
#pragma unroll
    for (int j = 0; j < 4; ++j) {
      const int dl = ty + j * 8;
      const float v = embed[(size_t)(d0 + dl) * KCODES + k0 + tx];
      tile[dl][tx] = v;
      sq += v * v;
    }
    part[ty][tx] = sq;
    __syncthreads();
    if (ty == 0) {
      float s = 0.f;
#pragma unroll
      for (int j = 0; j < 8; ++j) s += part[j][tx];
      enp[(size_t)(d0 >> 5) * KCODES + k0 + tx] = s;   // plain store, no race
    }
#pragma unroll
    for (int j = 0; j < 4; ++j) {
      const int kl = ty + j * 8;
      const size_t idx = (size_t)(k0 + kl) * DDIM + d0 + tx;
      const float v = tile[tx][kl];
      const unsigned short h = bf16rne(v);
      ehi[idx] = h;
      elo[idx] = bf16rne(v - __uint_as_float((unsigned)h << 16));
    }
  } else if (bid < 8192 + 4096 + 2048) {
    // ---- zero esumT (2048 blocks x 256 threads x 8 floats = DK) ----
    const int zb = bid - (8192 + 4096);
    const size_t off = (size_t)zb * 2048 + (size_t)tid * 8;
    const float4 z = {0.f, 0.f, 0.f, 0.f};
    *(float4*)&esumT[off] = z;
    *(float4*)&esumT[off + 4] = z;
  } else {
    // ---- misc init: 32 blocks ----
    const int b = bid - (8192 + 4096 + 2048);       // 0..31
    onehot[b * 256 + tid] = 0.f;
    const size_t pbase = (size_t)b * 1024 + (size_t)tid * 4;
    const ulonglong2 ff = {~0ull, ~0ull};
    *(ulonglong2*)&partials[pbase] = ff;
    *(ulonglong2*)&partials[pbase + 2] = ff;
    // cluster_size partial sum (256 values per block)
    float s = cluster_size[b * 256 + tid];
#pragma unroll
    for (int off = 32; off > 0; off >>= 1) s += __shfl_down(s, off);
    if ((tid & 63) == 0) w[tid >> 6] = s;
    __syncthreads();
    if (tid == 0) {
      scal[2 + b] = w[0] + w[1] + w[2] + w[3];
      if (b == 0) { scal[0] = 0.f; scal[1] = 0.f; }
    }
  }
}

// ============ K2: fused 3-product bf16-split MFMA dist GEMM + argmin ============
// proven 128x128 structure: BK=32, 4 waves, 2 barriers/K-step, 32 KB LDS.
__global__ __launch_bounds__(256) void argmin_mfma_kernel(
    const unsigned short* __restrict__ xhi, const unsigned short* __restrict__ xlo,
    const unsigned short* __restrict__ ehi, const unsigned short* __restrict__ elo,
    const float* __restrict__ enp, unsigned long long* __restrict__ partials) {
  __shared__ unsigned short Ahs[128 * 32];   // 8 KB each
  __shared__ unsigned short Als[128 * 32];
  __shared__ unsigned short Bhs[128 * 32];
  __shared__ unsigned short Bls[128 * 32];

  const int t    = threadIdx.x;
  const int wid  = t >> 6;
  const int lid  = t & 63;
  const int kblk = blockIdx.x;              // 0..63
  const int tokbase = blockIdx.y * 128;
  const int kbase   = kblk * 128;

  const int wrow = wid >> 1, wcol = wid & 1;    // 2x2 wave grid, 64x64 each
  const int m16  = lid & 15, kq = lid >> 4;

  const int srow = lid >> 2;                                  // 0..15
  const int gcol = ((lid & 3) ^ ((srow >> 1) & 3)) * 8;       // swizzled source
  const int fsw = (kq ^ ((m16 >> 1) & 3)) * 8;

  f32x4 acc[4][4];
#pragma unroll
  for (int i = 0; i < 4; ++i)
#pragma unroll
    for (int j = 0; j < 4; ++j) acc[i][j] = (f32x4)0.f;

  const unsigned short* Ahg = xhi + (size_t)tokbase * DDIM;
  const unsigned short* Alg = xlo + (size_t)tokbase * DDIM;
  const unsigned short* Bhg = ehi + (size_t)kbase * DDIM;
  const unsigned short* Blg = elo + (size_t)kbase * DDIM;

#pragma unroll 1
  for (int d0 = 0; d0 < DDIM; d0 += 32) {
    __syncthreads();
#pragma unroll
    for (int p = 0; p < 2; ++p) {
      const int chunk = wid + p * 4;                       // wave-uniform
      const size_t go = (size_t)(chunk * 16 + srow) * DDIM + d0 + gcol;
      gload_lds16(Ahg + go, &Ahs[chunk * 512]);
      gload_lds16(Alg + go, &Als[chunk * 512]);
      gload_lds16(Bhg + go, &Bhs[chunk * 512]);
      gload_lds16(Blg + go, &Bls[chunk * 512]);
    }
    __syncthreads();
    short8 bh[4], bl[4];
#pragma unroll
    for (int j = 0; j < 4; ++j) {
      const int r = (wcol * 64 + j * 16 + m16) * 32 + fsw;
      bh[j] = *(const short8*)&Bhs[r];
      bl[j] = *(const short8*)&Bls[r];
    }
#pragma unroll
    for (int i = 0; i < 4; ++i) {
      const int r = (wrow * 64 + i * 16 + m16) * 32 + fsw;
      const short8 ah = *(const short8*)&Ahs[r];
      const short8 al = *(const short8*)&Als[r];
#pragma unroll
      for (int j = 0; j < 4; ++j) {
        acc[i][j] = __builtin_amdgcn_mfma_f32_16x16x32_bf16(ah, bh[j], acc[i][j], 0, 0, 0);
        acc[i][j] = __builtin_amdgcn_mfma_f32_16x16x32_bf16(ah, bl[j], acc[i][j], 0, 0, 0);
        acc[i][j] = __builtin_amdgcn_mfma_f32_16x16x32_bf16(al, bh[j], acc[i][j], 0, 0, 0);
      }
    }
  }

  // ---- fused argmin epilogue: score = ||e_k||^2 - 2*dot ----
  float en[4];
#pragma unroll
  for (int j = 0; j < 4; ++j) {
    const int kk = kbase + wcol * 64 + j * 16 + m16;
    float s = 0.f;
#pragma unroll
    for (int b = 0; b < 16; ++b) s += enp[(size_t)b * KCODES + kk];
    en[j] = s;
  }

  __syncthreads();
  unsigned long long* red = (unsigned long long*)Ahs;   // [128][2], 2 KB
#pragma unroll
  for (int i = 0; i < 4; ++i) {
#pragma unroll
    for (int r = 0; r < 4; ++r) {
      unsigned long long best = 0xFFFFFFFFFFFFFFFFull;
#pragma unroll
      for (int j = 0; j < 4; ++j) {
        const float s = en[j] - 2.0f * acc[i][j][r];
        unsigned u = __float_as_uint(s);
        u = (u & 0x80000000u) ? ~u : (u | 0x80000000u);  // orderable bits
        const unsigned k = (unsigned)(kbase + wcol * 64 + j * 16 + m16);
        const unsigned long long c = ((unsigned long long)u << 32) | k;
        best = (c < best) ? c : best;
      }
#pragma unroll
      for (int s = 1; s < 16; s <<= 1) {
        const unsigned long long c = __shfl_xor(best, s);
        best = (c < best) ? c : best;
      }
      if (m16 == 0)
        red[(wrow * 64 + i * 16 + kq * 4 + r) * 2 + wcol] = best;
    }
  }
  __syncthreads();
  if (t < 128) {
    const unsigned long long a0 = red[t * 2], a1 = red[t * 2 + 1];
    const unsigned long long m = (a0 < a1) ? a0 : a1;
    atomicMin(&partials[tokbase + t], m);
  }
}

// ============ K3: gather quantize + EMA scatter stats + loss (2 tokens/block) ============
__global__ __launch_bounds__(256) void gather_stats_kernel(
    const float* __restrict__ x, const unsigned short* __restrict__ ehi,
    const unsigned short* __restrict__ elo,
    const unsigned long long* __restrict__ partials,
    float* __restrict__ quant_out, float* __restrict__ indf_out,
    float* __restrict__ embed_sumT, float* __restrict__ onehot,
    float* __restrict__ scal) {
  const int sub = threadIdx.x >> 7;          // 0/1: which token
  const int t7  = threadIdx.x & 127;
  const int n   = blockIdx.x * 2 + sub;
  __shared__ int s_ind[2];
  __shared__ float wsum[4];
  if (t7 == 0) {
    const int k = (int)(partials[n] & 0xFFFFFFFFull);
    s_ind[sub] = k;
    indf_out[n] = (float)k;
    atomicAdd(&onehot[k], 1.0f);
  }
  __syncthreads();
  const int k = s_ind[sub];
  const int d4 = t7 * 4;                     // 128 threads * 4 = 512 = DDIM
  const ushort4 h4 = *(const ushort4*)&ehi[(size_t)k * DDIM + d4];
  const ushort4 l4 = *(const ushort4*)&elo[(size_t)k * DDIM + d4];
  float4 e;
  e.x = __uint_as_float((unsigned)h4.x << 16) + __uint_as_float((unsigned)l4.x << 16);
  e.y = __uint_as_float((unsigned)h4.y << 16) + __uint_as_float((unsigned)l4.y << 16);
  e.z = __uint_as_float((unsigned)h4.z << 16) + __uint_as_float((unsigned)l4.z << 16);
  e.w = __uint_as_float((unsigned)h4.w << 16) + __uint_as_float((unsigned)l4.w << 16);
  const float4 xv = *(const float4*)&x[(size_t)n * DDIM + d4];
  *(float4*)&quant_out[(size_t)n * DDIM + d4] = e;
  atomicAdd(&embed_sumT[(size_t)k * DDIM + d4 + 0], xv.x);
  atomicAdd(&embed_sumT[(size_t)k * DDIM + d4 + 1], xv.y);
  atomicAdd(&embed_sumT[(size_t)k * DDIM + d4 + 2], xv.z);
  atomicAdd(&embed_sumT[(size_t)k * DDIM + d4 + 3], xv.w);
  const float dx0 = e.x - xv.x, dx1 = e.y - xv.y, dx2 = e.z - xv.z, dx3 = e.w - xv.w;
  float ls = dx0 * dx0 + dx1 * dx1 + dx2 * dx2 + dx3 * dx3;
#pragma unroll
  for (int off = 32; off > 0; off >>= 1) ls += __shfl_down(ls, off);
  if ((threadIdx.x & 63) == 0) wsum[threadIdx.x >> 6] = ls;
  __syncthreads();
  if (threadIdx.x == 0)
    atomicAdd(&scal[0], wsum[0] + wsum[1] + wsum[2] + wsum[3]);
}

// ============ K4: finalize (EMA avg + embed + ncs + loss; cluster fused) ============
// nsum computed analytically: 0.8*sum(cluster_size) + 0.2*NTOK (sum(onehot)=NTOK exact).
__global__ __launch_bounds__(256) void finalize_kernel(
    const float* __restrict__ embed_avg, const float* __restrict__ embed_sumT,
    const float* __restrict__ cluster_size, const float* __restrict__ onehot,
    const float* __restrict__ scal,
    float* __restrict__ out_embed, float* __restrict__ out_avg,
    float* __restrict__ out_ncs, float* __restrict__ out_loss) {
  __shared__ float tile[32][33];
  __shared__ float sh_nsum;
  const int k0 = blockIdx.x * 32;
  const int d0 = blockIdx.y * 32;
  const int tx = threadIdx.x & 31;
  const int ty = threadIdx.x >> 5;
  if (threadIdx.x == 0) {
    float s = 0.f;
#pragma unroll
    for (int b = 0; b < 32; ++b) s += scal[2 + b];
    sh_nsum = DECAYF * s + (1.0f - DECAYF) * (float)NTOK;
  }
#pragma unroll
  for (int j = 0; j < 4; ++j) {
    const int kl = ty + j * 8;
    tile[kl][tx] = embed_sumT[(size_t)(k0 + kl) * DDIM + d0 + tx];
  }
  __syncthreads();
  const float nsum = sh_nsum;
  const float ncs = DECAYF * cluster_size[k0 + tx] + (1.0f - DECAYF) * onehot[k0 + tx];
  const float csv = (ncs + EPSF) / (nsum + (float)KCODES * EPSF) * nsum;
#pragma unroll
  for (int j = 0; j < 4; ++j) {
    const int dl = ty + j * 8;
    const size_t idx = (size_t)(d0 + dl) * KCODES + k0 + tx;
    const float nea = DECAYF * embed_avg[idx] + (1.0f - DECAYF) * tile[tx][dl];
    out_avg[idx] = nea;
    out_embed[idx] = nea / csv;
  }
  if (blockIdx.y == 0 && threadIdx.x < 32)
    out_ncs[k0 + threadIdx.x] =
        DECAYF * cluster_size[k0 + threadIdx.x] + (1.0f - DECAYF) * onehot[k0 + threadIdx.x];
  if (blockIdx.x == 0 && blockIdx.y == 0 && threadIdx.x == 0)
    out_loss[0] = scal[0] * (1.0f / ((float)NTOK * (float)DDIM));
}

extern "C" void kernel_launch(void* const* d_in, const int* in_sizes, int n_in,
                              void* d_out, int out_size, void* d_ws, size_t ws_size,
                              hipStream_t stream) {
  (void)in_sizes; (void)n_in; (void)out_size; (void)ws_size;
  const float* x            = (const float*)d_in[0];   // [NTOK, 512]
  const float* embed        = (const float*)d_in[1];   // [D, K]
  const float* cluster_size = (const float*)d_in[2];   // [K]
  const float* embed_avg    = (const float*)d_in[3];   // [D, K]

  float* out = (float*)d_out;
  float* out_quant = out;                               // 16777216
  float* out_indf  = out + 16777216;                    // 32768
  float* out_loss  = out + 16777216 + 32768;            // 1
  float* out_embed = out + 16777216 + 32768 + 1;        // 4194304 (odd offset)
  float* out_ncs   = out_embed + DK;                    // 8192
  float* out_avg   = out_ncs + KCODES;                  // 4194304

  float* ws = (float*)d_ws;
  float* esumT  = ws + WS_ESUMT;
  float* onehot = ws + WS_ONEHOT;
  float* enp    = ws + WS_ENP;
  float* scal   = ws + WS_SCAL;
  unsigned long long* partials = (unsigned long long*)(ws + WS_PART);
  unsigned short* ehi = (unsigned short*)(ws + WS_EHI);
  unsigned short* elo = (unsigned short*)(ws + WS_ELO);

  // x hi/lo scratch lives in the out_quant region; overwritten by gather later.
  unsigned short* xhi = (unsigned short*)d_out;
  unsigned short* xlo = xhi + (size_t)NTOK * DDIM;

  // 4 dispatches total; no memsets (all init folded into prep_kernel).
  prep_kernel<<<8192 + 4096 + 2048 + 32, 256, 0, stream>>>(
      x, embed, cluster_size, xhi, xlo, ehi, elo, enp, esumT, onehot, scal, partials);

  argmin_mfma_kernel<<<dim3(64, 256), 256, 0, stream>>>(
      xhi, xlo, ehi, elo, enp, partials);

  gather_stats_kernel<<<NTOK / 2, 256, 0, stream>>>(
      x, ehi, elo, partials, out_quant, out_indf, esumT, onehot, scal);

  finalize_kernel<<<dim3(KCODES / 32, DDIM / 32), 256, 0, stream>>>(
      embed_avg, esumT, cluster_size, onehot, scal,
      out_embed, out_avg, out_ncs, out_loss);
}

// Round 4
// 1381.923 us; speedup vs baseline: 1.2873x; 1.0354x over previous
//
#include <hip/hip_runtime.h>

#define NTOK   32768
#define DDIM   512
#define KCODES 8192
#define DK     (DDIM * KCODES)      // 4194304
#define DECAYF 0.8f
#define EPSF   1e-5f

using short8 = __attribute__((ext_vector_type(8))) short;
using f32x4  = __attribute__((ext_vector_type(4))) float;

// ---------------- ws layout (float offsets) ----------------
// esumT [K][D] (zeroed in prep, atomic-accum in gather)
// onehot [K]   (zeroed in prep, atomic in gather)
// e_norm [K]   (plain-stored complete codebook norms, read by argmin)
// scal [64]    (0=loss accum; 2+b = cluster_size partial sums, b<32)
// partials NTOK u64 (0xFF-init in prep, atomicMin in argmin)
// ehi/elo [K][D] bf16 hi/lo codebook
#define WS_ESUMT  0
#define WS_ONEHOT DK
#define WS_ENORM  (DK + 8192)
#define WS_SCAL   (DK + 16384)
#define WS_PART   (WS_SCAL + 64)
#define WS_EHI    (WS_PART + 2 * NTOK)
#define WS_ELO    (WS_EHI + DK / 2)

__device__ __forceinline__ unsigned short bf16rne(float f) {
  unsigned u = __float_as_uint(f);
  unsigned r = u + 0x7FFFu + ((u >> 16) & 1u);
  return (unsigned short)(r >> 16);
}

__device__ __forceinline__ void gload_lds16(const unsigned short* g, unsigned short* l) {
  __builtin_amdgcn_global_load_lds(
      (const __attribute__((address_space(1))) unsigned int*)g,
      (__attribute__((address_space(3))) unsigned int*)l, 16, 0, 0);
}

// ============ K1: fused prep ============
// blocks [0,8192)          : split x into bf16 hi/lo
// blocks [8192,8448)       : transpose embed -> ehi/elo + COMPLETE e_norm (32 codes/block, full D)
// blocks [8448,10496)      : zero esumT
// blocks [10496,10528)     : zero onehot, partials=0xFF, cs partial sums, scal init
__global__ __launch_bounds__(256) void prep_kernel(
    const float* __restrict__ x, const float* __restrict__ embed,
    const float* __restrict__ cluster_size,
    unsigned short* __restrict__ xhi, unsigned short* __restrict__ xlo,
    unsigned short* __restrict__ ehi, unsigned short* __restrict__ elo,
    float* __restrict__ e_norm, float* __restrict__ esumT,
    float* __restrict__ onehot, float* __restrict__ scal,
    unsigned long long* __restrict__ partials) {
  __shared__ float tile[32][33];
  __shared__ float part[8][32];
  __shared__ float w[4];
  const int bid = blockIdx.x;
  const int tid = threadIdx.x;

  if (bid < 8192) {
    // ---- split x ----
    const size_t i = ((size_t)bid * 256 + tid) * 8;
    const float4 v0 = *(const float4*)&x[i];
    const float4 v1 = *(const float4*)&x[i + 4];
    const float v[8] = {v0.x, v0.y, v0.z, v0.w, v1.x, v1.y, v1.z, v1.w};
    unsigned short h[8], l[8];
#pragma unroll
    for (int j = 0; j < 8; ++j) {
      h[j] = bf16rne(v[j]);
      l[j] = bf16rne(v[j] - __uint_as_float((unsigned)h[j] << 16));
    }
    uint4 H, L;
    H.x = h[0] | ((unsigned)h[1] << 16); H.y = h[2] | ((unsigned)h[3] << 16);
    H.z = h[4] | ((unsigned)h[5] << 16); H.w = h[6] | ((unsigned)h[7] << 16);
    L.x = l[0] | ((unsigned)l[1] << 16); L.y = l[2] | ((unsigned)l[3] << 16);
    L.z = l[4] | ((unsigned)l[5] << 16); L.w = l[6] | ((unsigned)l[7] << 16);
    *(uint4*)&xhi[i] = H;
    *(uint4*)&xlo[i] = L;
  } else if (bid < 8192 + 256) {
    // ---- transpose embed: 32 codes/block, full D, complete norm ----
    const int k0 = (bid - 8192) * 32;
    const int tx = tid & 31;
    const int ty = tid >> 5;                     // 0..7
    float sq = 0.f;                               // partial norm for code k0+tx
#pragma unroll 1
    for (int d0 = 0; d0 < DDIM; d0 += 32) {
      __syncthreads();
#pragma unroll
      for (int j = 0; j < 4; ++j) {
        const int dl = ty + j * 8;
        const float v = embed[(size_t)(d0 + dl) * KCODES + k0 + tx];
        tile[dl][tx] = v;
        sq += v * v;
      }
      __syncthreads();
#pragma unroll
      for (int j = 0; j < 4; ++j) {
        const int kl = ty + j * 8;
        const size_t idx = (size_t)(k0 + kl) * DDIM + d0 + tx;
        const float v = tile[tx][kl];
        const unsigned short h = bf16rne(v);
        ehi[idx] = h;
        elo[idx] = bf16rne(v - __uint_as_float((unsigned)h << 16));
      }
    }
    part[ty][tx] = sq;
    __syncthreads();
    if (ty == 0) {
      float s = 0.f;
#pragma unroll
      for (int j = 0; j < 8; ++j) s += part[j][tx];
      e_norm[k0 + tx] = s;                       // plain store, complete value
    }
  } else if (bid < 8192 + 256 + 2048) {
    // ---- zero esumT (2048 blocks x 256 threads x 8 floats = DK) ----
    const int zb = bid - (8192 + 256);
    const size_t off = (size_t)zb * 2048 + (size_t)tid * 8;
    const float4 z = {0.f, 0.f, 0.f, 0.f};
    *(float4*)&esumT[off] = z;
    *(float4*)&esumT[off + 4] = z;
  } else {
    // ---- misc init: 32 blocks ----
    const int b = bid - (8192 + 256 + 2048);    // 0..31
    onehot[b * 256 + tid] = 0.f;
    const size_t pbase = (size_t)b * 1024 + (size_t)tid * 4;
    const ulonglong2 ff = {~0ull, ~0ull};
    *(ulonglong2*)&partials[pbase] = ff;
    *(ulonglong2*)&partials[pbase + 2] = ff;
    // cluster_size partial sum (256 values per block)
    float s = cluster_size[b * 256 + tid];
#pragma unroll
    for (int off = 32; off > 0; off >>= 1) s += __shfl_down(s, off);
    if ((tid & 63) == 0) w[tid >> 6] = s;
    __syncthreads();
    if (tid == 0) {
      scal[2 + b] = w[0] + w[1] + w[2] + w[3];
      if (b == 0) { scal[0] = 0.f; scal[1] = 0.f; }
    }
  }
}

// ============ K2: fused 3-product bf16-split MFMA dist GEMM + argmin ============
// proven 128x128 structure: BK=32, 4 waves, 2 barriers/K-step, 32 KB LDS.
__global__ __launch_bounds__(256) void argmin_mfma_kernel(
    const unsigned short* __restrict__ xhi, const unsigned short* __restrict__ xlo,
    const unsigned short* __restrict__ ehi, const unsigned short* __restrict__ elo,
    const float* __restrict__ e_norm, unsigned long long* __restrict__ partials) {
  __shared__ unsigned short Ahs[128 * 32];   // 8 KB each
  __shared__ unsigned short Als[128 * 32];
  __shared__ unsigned short Bhs[128 * 32];
  __shared__ unsigned short Bls[128 * 32];

  const int t    = threadIdx.x;
  const int wid  = t >> 6;
  const int lid  = t & 63;
  const int kblk = blockIdx.x;              // 0..63
  const int tokbase = blockIdx.y * 128;
  const int kbase   = kblk * 128;

  const int wrow = wid >> 1, wcol = wid & 1;    // 2x2 wave grid, 64x64 each
  const int m16  = lid & 15, kq = lid >> 4;

  const int srow = lid >> 2;                                  // 0..15
  const int gcol = ((lid & 3) ^ ((srow >> 1) & 3)) * 8;       // swizzled source
  const int fsw = (kq ^ ((m16 >> 1) & 3)) * 8;

  f32x4 acc[4][4];
#pragma unroll
  for (int i = 0; i < 4; ++i)
#pragma unroll
    for (int j = 0; j < 4; ++j) acc[i][j] = (f32x4)0.f;

  const unsigned short* Ahg = xhi + (size_t)tokbase * DDIM;
  const unsigned short* Alg = xlo + (size_t)tokbase * DDIM;
  const unsigned short* Bhg = ehi + (size_t)kbase * DDIM;
  const unsigned short* Blg = elo + (size_t)kbase * DDIM;

#pragma unroll 1
  for (int d0 = 0; d0 < DDIM; d0 += 32) {
    __syncthreads();
#pragma unroll
    for (int p = 0; p < 2; ++p) {
      const int chunk = wid + p * 4;                       // wave-uniform
      const size_t go = (size_t)(chunk * 16 + srow) * DDIM + d0 + gcol;
      gload_lds16(Ahg + go, &Ahs[chunk * 512]);
      gload_lds16(Alg + go, &Als[chunk * 512]);
      gload_lds16(Bhg + go, &Bhs[chunk * 512]);
      gload_lds16(Blg + go, &Bls[chunk * 512]);
    }
    __syncthreads();
    short8 bh[4], bl[4];
#pragma unroll
    for (int j = 0; j < 4; ++j) {
      const int r = (wcol * 64 + j * 16 + m16) * 32 + fsw;
      bh[j] = *(const short8*)&Bhs[r];
      bl[j] = *(const short8*)&Bls[r];
    }
#pragma unroll
    for (int i = 0; i < 4; ++i) {
      const int r = (wrow * 64 + i * 16 + m16) * 32 + fsw;
      const short8 ah = *(const short8*)&Ahs[r];
      const short8 al = *(const short8*)&Als[r];
#pragma unroll
      for (int j = 0; j < 4; ++j) {
        acc[i][j] = __builtin_amdgcn_mfma_f32_16x16x32_bf16(ah, bh[j], acc[i][j], 0, 0, 0);
        acc[i][j] = __builtin_amdgcn_mfma_f32_16x16x32_bf16(ah, bl[j], acc[i][j], 0, 0, 0);
        acc[i][j] = __builtin_amdgcn_mfma_f32_16x16x32_bf16(al, bh[j], acc[i][j], 0, 0, 0);
      }
    }
  }

  // ---- fused argmin epilogue: score = ||e_k||^2 - 2*dot ----
  float en[4];
#pragma unroll
  for (int j = 0; j < 4; ++j)
    en[j] = e_norm[kbase + wcol * 64 + j * 16 + m16];

  __syncthreads();
  unsigned long long* red = (unsigned long long*)Ahs;   // [128][2], 2 KB
#pragma unroll
  for (int i = 0; i < 4; ++i) {
#pragma unroll
    for (int r = 0; r < 4; ++r) {
      unsigned long long best = 0xFFFFFFFFFFFFFFFFull;
#pragma unroll
      for (int j = 0; j < 4; ++j) {
        const float s = en[j] - 2.0f * acc[i][j][r];
        unsigned u = __float_as_uint(s);
        u = (u & 0x80000000u) ? ~u : (u | 0x80000000u);  // orderable bits
        const unsigned k = (unsigned)(kbase + wcol * 64 + j * 16 + m16);
        const unsigned long long c = ((unsigned long long)u << 32) | k;
        best = (c < best) ? c : best;
      }
#pragma unroll
      for (int s = 1; s < 16; s <<= 1) {
        const unsigned long long c = __shfl_xor(best, s);
        best = (c < best) ? c : best;
      }
      if (m16 == 0)
        red[(wrow * 64 + i * 16 + kq * 4 + r) * 2 + wcol] = best;
    }
  }
  __syncthreads();
  if (t < 128) {
    const unsigned long long a0 = red[t * 2], a1 = red[t * 2 + 1];
    const unsigned long long m = (a0 < a1) ? a0 : a1;
    atomicMin(&partials[tokbase + t], m);
  }
}

// ============ K3: gather quantize + EMA scatter stats + loss (2 tokens/block) ============
__global__ __launch_bounds__(256) void gather_stats_kernel(
    const float* __restrict__ x, const unsigned short* __restrict__ ehi,
    const unsigned short* __restrict__ elo,
    const unsigned long long* __restrict__ partials,
    float* __restrict__ quant_out, float* __restrict__ indf_out,
    float* __restrict__ embed_sumT, float* __restrict__ onehot,
    float* __restrict__ scal) {
  const int sub = threadIdx.x >> 7;          // 0/1: which token
  const int t7  = threadIdx.x & 127;
  const int n   = blockIdx.x * 2 + sub;
  __shared__ int s_ind[2];
  __shared__ float wsum[4];
  if (t7 == 0) {
    const int k = (int)(partials[n] & 0xFFFFFFFFull);
    s_ind[sub] = k;
    indf_out[n] = (float)k;
    atomicAdd(&onehot[k], 1.0f);
  }
  __syncthreads();
  const int k = s_ind[sub];
  const int d4 = t7 * 4;                     // 128 threads * 4 = 512 = DDIM
  const ushort4 h4 = *(const ushort4*)&ehi[(size_t)k * DDIM + d4];
  const ushort4 l4 = *(const ushort4*)&elo[(size_t)k * DDIM + d4];
  float4 e;
  e.x = __uint_as_float((unsigned)h4.x << 16) + __uint_as_float((unsigned)l4.x << 16);
  e.y = __uint_as_float((unsigned)h4.y << 16) + __uint_as_float((unsigned)l4.y << 16);
  e.z = __uint_as_float((unsigned)h4.z << 16) + __uint_as_float((unsigned)l4.z << 16);
  e.w = __uint_as_float((unsigned)h4.w << 16) + __uint_as_float((unsigned)l4.w << 16);
  const float4 xv = *(const float4*)&x[(size_t)n * DDIM + d4];
  *(float4*)&quant_out[(size_t)n * DDIM + d4] = e;
  atomicAdd(&embed_sumT[(size_t)k * DDIM + d4 + 0], xv.x);
  atomicAdd(&embed_sumT[(size_t)k * DDIM + d4 + 1], xv.y);
  atomicAdd(&embed_sumT[(size_t)k * DDIM + d4 + 2], xv.z);
  atomicAdd(&embed_sumT[(size_t)k * DDIM + d4 + 3], xv.w);
  const float dx0 = e.x - xv.x, dx1 = e.y - xv.y, dx2 = e.z - xv.z, dx3 = e.w - xv.w;
  float ls = dx0 * dx0 + dx1 * dx1 + dx2 * dx2 + dx3 * dx3;
#pragma unroll
  for (int off = 32; off > 0; off >>= 1) ls += __shfl_down(ls, off);
  if ((threadIdx.x & 63) == 0) wsum[threadIdx.x >> 6] = ls;
  __syncthreads();
  if (threadIdx.x == 0)
    atomicAdd(&scal[0], wsum[0] + wsum[1] + wsum[2] + wsum[3]);
}

// ============ K4: finalize (EMA avg + embed + ncs + loss; cluster fused) ============
// nsum computed analytically: 0.8*sum(cluster_size) + 0.2*NTOK (sum(onehot)=NTOK exact).
__global__ __launch_bounds__(256) void finalize_kernel(
    const float* __restrict__ embed_avg, const float* __restrict__ embed_sumT,
    const float* __restrict__ cluster_size, const float* __restrict__ onehot,
    const float* __restrict__ scal,
    float* __restrict__ out_embed, float* __restrict__ out_avg,
    float* __restrict__ out_ncs, float* __restrict__ out_loss) {
  __shared__ float tile[32][33];
  __shared__ float sh_nsum;
  const int k0 = blockIdx.x * 32;
  const int d0 = blockIdx.y * 32;
  const int tx = threadIdx.x & 31;
  const int ty = threadIdx.x >> 5;
  if (threadIdx.x == 0) {
    float s = 0.f;
#pragma unroll
    for (int b = 0; b < 32; ++b) s += scal[2 + b];
    sh_nsum = DECAYF * s + (1.0f - DECAYF) * (float)NTOK;
  }
#pragma unroll
  for (int j = 0; j < 4; ++j) {
    const int kl = ty + j * 8;
    tile[kl][tx] = embed_sumT[(size_t)(k0 + kl) * DDIM + d0 + tx];
  }
  __syncthreads();
  const float nsum = sh_nsum;
  const float ncs = DECAYF * cluster_size[k0 + tx] + (1.0f - DECAYF) * onehot[k0 + tx];
  const float csv = (ncs + EPSF) / (nsum + (float)KCODES * EPSF) * nsum;
#pragma unroll
  for (int j = 0; j < 4; ++j) {
    const int dl = ty + j * 8;
    const size_t idx = (size_t)(d0 + dl) * KCODES + k0 + tx;
    const float nea = DECAYF * embed_avg[idx] + (1.0f - DECAYF) * tile[tx][dl];
    out_avg[idx] = nea;
    out_embed[idx] = nea / csv;
  }
  if (blockIdx.y == 0 && ty == 0)
    out_ncs[k0 + tx] = ncs;
  if (blockIdx.x == 0 && blockIdx.y == 0 && threadIdx.x == 0)
    out_loss[0] = scal[0] * (1.0f / ((float)NTOK * (float)DDIM));
}

extern "C" void kernel_launch(void* const* d_in, const int* in_sizes, int n_in,
                              void* d_out, int out_size, void* d_ws, size_t ws_size,
                              hipStream_t stream) {
  (void)in_sizes; (void)n_in; (void)out_size; (void)ws_size;
  const float* x            = (const float*)d_in[0];   // [NTOK, 512]
  const float* embed        = (const float*)d_in[1];   // [D, K]
  const float* cluster_size = (const float*)d_in[2];   // [K]
  const float* embed_avg    = (const float*)d_in[3];   // [D, K]

  float* out = (float*)d_out;
  float* out_quant = out;                               // 16777216
  float* out_indf  = out + 16777216;                    // 32768
  float* out_loss  = out + 16777216 + 32768;            // 1
  float* out_embed = out + 16777216 + 32768 + 1;        // 4194304 (odd offset)
  float* out_ncs   = out_embed + DK;                    // 8192
  float* out_avg   = out_ncs + KCODES;                  // 4194304

  float* ws = (float*)d_ws;
  float* esumT  = ws + WS_ESUMT;
  float* onehot = ws + WS_ONEHOT;
  float* e_norm = ws + WS_ENORM;
  float* scal   = ws + WS_SCAL;
  unsigned long long* partials = (unsigned long long*)(ws + WS_PART);
  unsigned short* ehi = (unsigned short*)(ws + WS_EHI);
  unsigned short* elo = (unsigned short*)(ws + WS_ELO);

  // x hi/lo scratch lives in the out_quant region; overwritten by gather later.
  unsigned short* xhi = (unsigned short*)d_out;
  unsigned short* xlo = xhi + (size_t)NTOK * DDIM;

  // 4 dispatches total; no memsets (all init folded into prep_kernel).
  prep_kernel<<<8192 + 256 + 2048 + 32, 256, 0, stream>>>(
      x, embed, cluster_size, xhi, xlo, ehi, elo, e_norm, esumT, onehot, scal, partials);

  argmin_mfma_kernel<<<dim3(64, 256), 256, 0, stream>>>(
      xhi, xlo, ehi, elo, e_norm, partials);

  gather_stats_kernel<<<NTOK / 2, 256, 0, stream>>>(
      x, ehi, elo, partials, out_quant, out_indf, esumT, onehot, scal);

  finalize_kernel<<<dim3(KCODES / 32, DDIM / 32), 256, 0, stream>>>(
      embed_avg, esumT, cluster_size, onehot, scal,
      out_embed, out_avg, out_ncs, out_loss);
}